// Round 7
// baseline (127.303 us; speedup 1.0000x reference)
//
#include <hip/hip_runtime.h>
#include <math.h>

#define CC 64
#define HWN 4096
#define QB 64            // q per block; ALL 8 waves compute the same 64 q
#define KSPLIT 8         // each wave privately owns 512 k
#define KT 32
#define NITER (HWN / KSPLIT / KT)   // 16 chunks per wave
#define NPAIR (NITER / 2)           // 8 chunk-pairs

typedef __attribute__((ext_vector_type(8))) short bf16x8;
typedef __attribute__((ext_vector_type(4))) float f32x4;

// precomputed bf16 operand layouts (written by prep_kernel every launch)
__device__ __align__(16) unsigned short g_bgT[4][HWN][CC];  // (bg*sb)^T  [b][k][c]
__device__ __align__(16) unsigned short g_bgN[4][CC][HWN];  // bf16(bg)   [b][c][k]
__device__ __align__(16) unsigned short g_fgT[4][HWN][CC];  // (fg*sf)^T  [b][q][c]

static __device__ __forceinline__ unsigned int f2bf(float x) {   // RNE
  union { float f; unsigned int u; } v; v.f = x;
  return (v.u + 0x7fffu + ((v.u >> 16) & 1u)) >> 16;
}
static __device__ __forceinline__ unsigned int packbf(float lo, float hi) {
  return f2bf(lo) | (f2bf(hi) << 16);
}

// ---- prep: fused column norms + bf16 operand layouts (r5 version, bgN restored) ----
// grid 512 = which(2) x b(4) x ktile(64), 256 threads
__global__ __launch_bounds__(256) void prep_kernel(const float* __restrict__ bg,
                                                   const float* __restrict__ fg) {
  __shared__ float lds[64 * 65];   // [k][c], stride 65 (2-way banks everywhere)
  const int bid = blockIdx.x;
  const int kt = bid & 63, b = (bid >> 6) & 3, which = bid >> 8;
  const float* src = (which ? fg : bg) + (size_t)b * CC * HWN + kt * 64;
  const int tid = threadIdx.x;

  // stage tile transposed: thread loads [c][k-range] float4, writes lds[k][c]
  {
    int c = tid >> 2, k0 = (tid & 3) * 16;
#pragma unroll
    for (int j4 = 0; j4 < 4; ++j4) {
      float4 v = *(const float4*)(src + (size_t)c * HWN + k0 + 4 * j4);
      lds[(k0 + 4 * j4 + 0) * 65 + c] = v.x;
      lds[(k0 + 4 * j4 + 1) * 65 + c] = v.y;
      lds[(k0 + 4 * j4 + 2) * 65 + c] = v.z;
      lds[(k0 + 4 * j4 + 3) * 65 + c] = v.w;
    }
  }
  __syncthreads();

  const int k = tid >> 2, u = tid & 3;
  // column norm: 4 threads per k, each sums 16 c, combine via shfl
  float ss = 0.f;
#pragma unroll
  for (int j = 0; j < 16; ++j) {
    float v = lds[k * 65 + u * 16 + j];
    ss = fmaf(v, v, ss);
  }
  ss += __shfl_xor(ss, 1, 64);
  ss += __shfl_xor(ss, 2, 64);
  const float s = 1.0f / fmaxf(sqrtf(ss), 1e-12f);

  // write scaled transposed [b][k][c] bf16
  {
    unsigned int* gT32 = (unsigned int*)(which ? &g_fgT[0][0][0] : &g_bgT[0][0][0]);
    size_t R = (size_t)b * HWN + kt * 64 + k;
    unsigned int w8[8];
#pragma unroll
    for (int i = 0; i < 8; ++i) {
      int c2 = u * 16 + 2 * i;
      w8[i] = packbf(lds[k * 65 + c2] * s, lds[k * 65 + c2 + 1] * s);
    }
    *(uint4*)&gT32[R * 32 + u * 8]     = make_uint4(w8[0], w8[1], w8[2], w8[3]);
    *(uint4*)&gT32[R * 32 + u * 8 + 4] = make_uint4(w8[4], w8[5], w8[6], w8[7]);
  }

  // bg blocks also write raw cast [b][c][k] bf16
  if (which == 0) {
    unsigned int* gN32 = (unsigned int*)&g_bgN[0][0][0];
    int cN = tid >> 2, vN = tid & 3;
    unsigned int n8[8];
#pragma unroll
    for (int i = 0; i < 8; ++i) {
      int kk = vN * 16 + 2 * i;
      n8[i] = packbf(lds[kk * 65 + cN], lds[(kk + 1) * 65 + cN]);
    }
    size_t RN = ((size_t)b * CC + cN) * (HWN / 2) + kt * 32 + vN * 8;
    *(uint4*)&gN32[RN]     = make_uint4(n8[0], n8[1], n8[2], n8[3]);
    *(uint4*)&gN32[RN + 4] = make_uint4(n8[4], n8[5], n8[6], n8[7]);
  }
}

// ---- flash attention: r5 structure + chunk-pair bgN loads (full 128B line use) ----
// Wall: ~45 GB/s/CU line-granular VMEM delivery (r3/r4 measured). r5 fetched each
// bgN 128B line twice (64B per chunk, L1 evicted between chunks). Here both 64B
// halves of each line are loaded back-to-back (reuse distance 0 -> L1 hit):
// bgN effective traffic 256->128 MB, total 384->256 MB.
// Pair pipeline: per pair p {stage ch2p+1; load pair p+1 (8 regs); vmcnt(12);
// compute ch2p; stage ch2p+2; vmcnt(12); compute ch2p+1}. Tail: vmcnt(4)/(0).
// LDS: [0,65536)        bgT staging, wave w: [w*8192 + buf*4096), swizzled
//      [65536,106496)   P per wave [64q][40k] ushort (5120 B each)
//      [106496,108544)  mL [8ks][64q] f32
//      epilogue aliases [0,69632) as mO [8ks][64c][34] f32 (two q-half passes)
#define P_OFF 65536
#define ML_OFF 106496
#define SMEM_BYTES 108544
__global__ __launch_bounds__(512, 2) void attn_kernel(const float* __restrict__ fg,
                                                      const float* __restrict__ mask,
                                                      float* __restrict__ out) {
  __shared__ __align__(16) char smem[SMEM_BYTES];
  // bijective XCD swizzle (256 % 8 == 0): 2 XCDs per batch -> 2MB working set/L2
  const int wg = blockIdx.x;
  const int wgp = (wg & 7) * 32 + (wg >> 3);
  const int b = wgp >> 6;
  const int q0 = (wgp & 63) * QB;
  const int tid = threadIdx.x;
  const int lane = tid & 63;
  const int ks = tid >> 6;    // 0..7, private K-split (512 k each)
  const int m16 = lane & 15;
  const int quad = lane >> 4;

  // fg B-fragments (64 q), loaded once from global (L2)
  bf16x8 Bf[4][2];
#pragma unroll
  for (int qf = 0; qf < 4; ++qf)
#pragma unroll
    for (int h = 0; h < 2; ++h)
      Bf[qf][h] = *(const bf16x8*)&g_fgT[b][q0 + qf * 16 + m16][h * 32 + quad * 8];

  // bgT lane-swizzled staging sources (swizzle on global side; LDS lane-ordered)
  const unsigned short* srcT[4];
#pragma unroll
  for (int t = 0; t < 4; ++t) {
    int uT = t * 64 + lane;
    int kk = uT >> 3, pos = uT & 7, j = pos ^ (kk & 7);
    srcT[t] = &g_bgT[b][ks * 512 + kk][j * 8];
  }

  // bgN per-lane base: PV A fragment row c = 16t+m16, k-slice = quad*8
  const unsigned short* pN = &g_bgN[b][m16][ks * 512 + quad * 8];

  unsigned short* P = (unsigned short*)(smem + P_OFF + ks * 5120);  // [64 q][40 k]
  float* mL = (float*)(smem + ML_OFF);

  float l_run[4] = {0.f, 0.f, 0.f, 0.f};   // per-lane partial sums per q-frag
  f32x4 O[4][4];                            // [c-tile][q-frag]
#pragma unroll
  for (int t = 0; t < 4; ++t)
#pragma unroll
    for (int qf = 0; qf < 4; ++qf) O[t][qf] = (f32x4){0.f, 0.f, 0.f, 0.f};

  char* const myT = smem + ks * 8192;       // this wave's bgT staging (2 x 4KB)

  auto stageT = [&](int bufsel) {
#pragma unroll
    for (int t = 0; t < 4; ++t) {
      __builtin_amdgcn_global_load_lds(
          (const __attribute__((address_space(1))) unsigned int*)srcT[t],
          (__attribute__((address_space(3))) unsigned int*)(myT + bufsel * 4096 + t * 1024),
          16, 0, 0);
      srcT[t] += KT * CC;   // next chunk
    }
  };

  // chunk-pair bgN load: A[t] = chunk 2pp (lo 64B of line), A[4+t] = chunk 2pp+1
  // (hi 64B of the SAME 128B line) -- adjacent issue => second access L1-hits.
  bf16x8 A8a[8], A8b[8];
  auto loadNpair = [&](bf16x8 (&A)[8], int pp) {
#pragma unroll
    for (int t = 0; t < 4; ++t) {
      const unsigned short* rowp = pN + (size_t)t * 16 * HWN + pp * 64;
      A[t]     = *(const bf16x8*)(rowp);
      A[4 + t] = *(const bf16x8*)(rowp + 32);
    }
  };

  // compute one chunk from LDS buffer `co` using A-frags A[ab..ab+3]
  auto computeChunk = [&](int co, const bf16x8 (&A)[8], int ab) {
    const char* baseT = myT + co * 4096;

    // scores S[32k][64q] = (bg*sb)^T · (fg*sf): 4 ds_read feed 16 MFMA
    f32x4 S[4][2];
    __builtin_amdgcn_s_setprio(1);
#pragma unroll
    for (int i = 0; i < 2; ++i) {
      int kk = 16 * i + m16;
      bf16x8 T0 = *(const bf16x8*)(baseT + kk * 128 + ((quad) ^ (kk & 7)) * 16);
      bf16x8 T1 = *(const bf16x8*)(baseT + kk * 128 + ((4 + quad) ^ (kk & 7)) * 16);
#pragma unroll
      for (int qf = 0; qf < 4; ++qf) {
        f32x4 acc = {0.f, 0.f, 0.f, 0.f};
        acc = __builtin_amdgcn_mfma_f32_16x16x32_bf16(T0, Bf[qf][0], acc, 0, 0, 0);
        acc = __builtin_amdgcn_mfma_f32_16x16x32_bf16(T1, Bf[qf][1], acc, 0, 0, 0);
        S[qf][i] = acc;
      }
    }
    __builtin_amdgcn_s_setprio(0);

    // fixed-max softmax: cosines, |s| <= 1 -> p = exp(s-1); per-lane deferred sum
#pragma unroll
    for (int qf = 0; qf < 4; ++qf)
#pragma unroll
      for (int i = 0; i < 2; ++i) {
        float pe[4];
#pragma unroll
        for (int r = 0; r < 4; ++r) {
          pe[r] = __expf(S[qf][i][r] - 1.0f);
          l_run[qf] += pe[r];
        }
        // pack P -> per-wave LDS [q][k] bf16 (round-half-up via +0x8000, v_perm)
        union { float f; unsigned int u; } x0, x1, x2, x3;
        x0.f = pe[0]; x1.f = pe[1]; x2.f = pe[2]; x3.f = pe[3];
        unsigned int p01 = __builtin_amdgcn_perm(x1.u + 0x8000u, x0.u + 0x8000u, 0x07060302u);
        unsigned int p23 = __builtin_amdgcn_perm(x3.u + 0x8000u, x2.u + 0x8000u, 0x07060302u);
        *(uint2*)&P[(qf * 16 + m16) * 40 + 16 * i + quad * 4] = make_uint2(p01, p23);
      }

    // PV: O[c][q] += bg[c][k] · P[k][q]   (per-wave P + private regs: no barrier)
    bf16x8 Pf[4];
#pragma unroll
    for (int qf = 0; qf < 4; ++qf)
      Pf[qf] = *(const bf16x8*)&P[(qf * 16 + m16) * 40 + quad * 8];
    __builtin_amdgcn_s_setprio(1);
#pragma unroll
    for (int t = 0; t < 4; ++t)
#pragma unroll
      for (int qf = 0; qf < 4; ++qf)
        O[t][qf] = __builtin_amdgcn_mfma_f32_16x16x32_bf16(A[ab + t], Pf[qf], O[t][qf], 0, 0, 0);
    __builtin_amdgcn_s_setprio(0);
  };

  // one pair step: compute chunks 2pp (buf0) and 2pp+1 (buf1) from `cur`,
  // prefetching pair pp+1 into `nxt` and the next two bgT chunks.
  auto pairStep = [&](int pp, bf16x8 (&cur)[8], bf16x8 (&nxt)[8]) {
    // first half: chunk 2pp from buf0
    stageT(1);                          // bgT chunk 2pp+1 -> buf1 (4 glds)
    if (pp + 1 < NPAIR) {
      loadNpair(nxt, pp + 1);           // 8 reg loads
      // outstanding: [cur-pair(8)?, bgT-2pp(4)] oldest + 12 newer -> wait 12
      asm volatile("s_waitcnt vmcnt(12)" ::: "memory");
    } else {
      asm volatile("s_waitcnt vmcnt(4)" ::: "memory");   // only bgT-2pp+1 newer
    }
    computeChunk(0, cur, 0);
    // second half: chunk 2pp+1 from buf1
    if (pp + 1 < NPAIR) {
      stageT(0);                        // bgT chunk 2pp+2 -> buf0
      asm volatile("s_waitcnt vmcnt(12)" ::: "memory");   // bgT-2pp+1 done
    } else {
      asm volatile("s_waitcnt vmcnt(0)" ::: "memory");
    }
    computeChunk(1, cur, 4);
  };

  // prologue: chunk 0 bgT + pair 0 bgN in flight
  stageT(0);
  loadNpair(A8a, 0);

  for (int p2 = 0; p2 < NPAIR; p2 += 2) {
    pairStep(p2,     A8a, A8b);
    pairStep(p2 + 1, A8b, A8a);
  }

  // ---- merge 8 K-splits + epilogue (two q-half passes; mO aliases staging+P) ----
#pragma unroll
  for (int qf = 0; qf < 4; ++qf) {
    l_run[qf] += __shfl_xor(l_run[qf], 16, 64);
    l_run[qf] += __shfl_xor(l_run[qf], 32, 64);
  }
  if (quad == 0) {
#pragma unroll
    for (int qf = 0; qf < 4; ++qf) mL[ks * 64 + qf * 16 + m16] = l_run[qf];
  }
  float* mO = (float*)smem;   // [8 ks][64 c][34]
  const float* fgB = fg + (size_t)b * CC * HWN;
  const float* mk = mask + (size_t)b * HWN;
  float* outB = out + (size_t)b * CC * HWN;

#pragma unroll
  for (int half = 0; half < 2; ++half) {
    __syncthreads();   // pass 0: all waves done with staging/P reads; pass 1: reduce done
#pragma unroll
    for (int qh = 0; qh < 2; ++qh) {
      int qf = half * 2 + qh;
#pragma unroll
      for (int t = 0; t < 4; ++t)
#pragma unroll
        for (int r = 0; r < 4; ++r)
          mO[(ks * 64 + 16 * t + quad * 4 + r) * 34 + qh * 16 + m16] = O[t][qf][r];
    }
    __syncthreads();
    {
      int q = tid & 31, cb = tid >> 5;   // cb 0..15
      int qglob = q0 + half * 32 + q;
      float L = 0.f;
#pragma unroll
      for (int s = 0; s < 8; ++s) L += mL[s * 64 + half * 32 + q];
      float invL = 1.0f / L;
      float mv = mk[qglob];
#pragma unroll
      for (int e = 0; e < 4; ++e) {
        int c = cb * 4 + e;
        float acc = 0.f;
#pragma unroll
        for (int s = 0; s < 8; ++s) acc += mO[(s * 64 + c) * 34 + q];
        float att = acc * invL;
        float fgv = fgB[(size_t)c * HWN + qglob];
        outB[(size_t)c * HWN + qglob] = fgv + mv * (att - fgv);
      }
    }
  }
}

extern "C" void kernel_launch(void* const* d_in, const int* in_sizes, int n_in,
                              void* d_out, int out_size, void* d_ws, size_t ws_size,
                              hipStream_t stream) {
  const float* background = (const float*)d_in[0];
  const float* foreground = (const float*)d_in[1];
  const float* mask       = (const float*)d_in[2];
  float* out = (float*)d_out;
  prep_kernel<<<512, 256, 0, stream>>>(background, foreground);
  attn_kernel<<<dim3(HWN / QB * 4), 512, 0, stream>>>(foreground, mask, out);
}

// Round 8
// 91.745 us; speedup vs baseline: 1.3876x; 1.3876x over previous
//
#include <hip/hip_runtime.h>
#include <math.h>

#define CC 64
#define HWN 4096
#define QB 64            // q per block; ALL 8 waves compute the same 64 q
#define KSPLIT 8         // each wave privately owns 512 k
#define KT 32
#define NITER (HWN / KSPLIT / KT)   // 16 chunks per wave
#define NKC (HWN / KT)              // 128 k-chunks per batch

typedef __attribute__((ext_vector_type(8))) short bf16x8;
typedef __attribute__((ext_vector_type(4))) float f32x4;

// precomputed bf16 operand layouts (written by prep_kernel every launch)
__device__ __align__(16) unsigned short g_bgT[4][HWN][CC];       // (bg*sb)^T [b][k][c]
__device__ __align__(16) unsigned short g_bgN[4][NKC][CC][KT];   // bf16(bg) chunk-major
__device__ __align__(16) unsigned short g_fgT[4][HWN][CC];       // (fg*sf)^T [b][q][c]

static __device__ __forceinline__ unsigned int f2bf(float x) {   // RNE
  union { float f; unsigned int u; } v; v.f = x;
  return (v.u + 0x7fffu + ((v.u >> 16) & 1u)) >> 16;
}
static __device__ __forceinline__ unsigned int packbf(float lo, float hi) {
  return f2bf(lo) | (f2bf(hi) << 16);
}

// ---- prep: fused column norms + bf16 operand layouts ----
// grid 512 = which(2) x b(4) x ktile(64), 256 threads
// g_bgN is chunk-major [b][kc][c][32k]: each 4KB block is one chunk's PV operand,
// every 128B line = two adjacent c-rows, fully consumed by one wave's loads.
__global__ __launch_bounds__(256) void prep_kernel(const float* __restrict__ bg,
                                                   const float* __restrict__ fg) {
  __shared__ float lds[64 * 65];   // [k][c], stride 65 (2-way banks everywhere)
  const int bid = blockIdx.x;
  const int kt = bid & 63, b = (bid >> 6) & 3, which = bid >> 8;
  const float* src = (which ? fg : bg) + (size_t)b * CC * HWN + kt * 64;
  const int tid = threadIdx.x;

  // stage tile transposed: thread loads [c][k-range] float4, writes lds[k][c]
  {
    int c = tid >> 2, k0 = (tid & 3) * 16;
#pragma unroll
    for (int j4 = 0; j4 < 4; ++j4) {
      float4 v = *(const float4*)(src + (size_t)c * HWN + k0 + 4 * j4);
      lds[(k0 + 4 * j4 + 0) * 65 + c] = v.x;
      lds[(k0 + 4 * j4 + 1) * 65 + c] = v.y;
      lds[(k0 + 4 * j4 + 2) * 65 + c] = v.z;
      lds[(k0 + 4 * j4 + 3) * 65 + c] = v.w;
    }
  }
  __syncthreads();

  const int k = tid >> 2, u = tid & 3;
  // column norm: 4 threads per k, each sums 16 c, combine via shfl
  float ss = 0.f;
#pragma unroll
  for (int j = 0; j < 16; ++j) {
    float v = lds[k * 65 + u * 16 + j];
    ss = fmaf(v, v, ss);
  }
  ss += __shfl_xor(ss, 1, 64);
  ss += __shfl_xor(ss, 2, 64);
  const float s = 1.0f / fmaxf(sqrtf(ss), 1e-12f);

  // write scaled transposed [b][k][c] bf16
  {
    unsigned int* gT32 = (unsigned int*)(which ? &g_fgT[0][0][0] : &g_bgT[0][0][0]);
    size_t R = (size_t)b * HWN + kt * 64 + k;
    unsigned int w8[8];
#pragma unroll
    for (int i = 0; i < 8; ++i) {
      int c2 = u * 16 + 2 * i;
      w8[i] = packbf(lds[k * 65 + c2] * s, lds[k * 65 + c2 + 1] * s);
    }
    *(uint4*)&gT32[R * 32 + u * 8]     = make_uint4(w8[0], w8[1], w8[2], w8[3]);
    *(uint4*)&gT32[R * 32 + u * 8 + 4] = make_uint4(w8[4], w8[5], w8[6], w8[7]);
  }

  // bg blocks also write raw cast, chunk-major: [b][kc][c][32]
  if (which == 0) {
    unsigned int* gN32 = (unsigned int*)&g_bgN[0][0][0][0];
    int cN = tid >> 2, vN = tid & 3;   // vN covers k = vN*16 .. +15 of this 64-k tile
    unsigned int n8[8];
#pragma unroll
    for (int i = 0; i < 8; ++i) {
      int kk = vN * 16 + 2 * i;
      n8[i] = packbf(lds[kk * 65 + cN], lds[(kk + 1) * 65 + cN]);
    }
    int kc = kt * 2 + (vN >> 1);           // global chunk index within batch
    size_t RN = (((size_t)b * NKC + kc) * CC + cN) * (KT / 2) + (vN & 1) * 8;
    *(uint4*)&gN32[RN]     = make_uint4(n8[0], n8[1], n8[2], n8[3]);
    *(uint4*)&gN32[RN + 4] = make_uint4(n8[4], n8[5], n8[6], n8[7]);
  }
}

// ---- flash attention: r5 structure + chunk-major bgN (full 128B line use) ----
// Wall: ~45 GB/s/CU line-granular VMEM delivery (r3/r4 measured). r5's bgN stream
// fetched each 128B line twice (64B/chunk, L1-evicted between chunks); r7's
// register pair-fix spilled (VGPR 128, 98MB scratch writes). This round fixes it
// in LAYOUT: chunk-major g_bgN makes each chunk's 4KB dense, lines fully used,
// register shape identical to r5. Effective traffic 384 -> 256 MB.
// LDS: [0,65536)        bgT staging, wave w: [w*8192 + buf*4096), swizzled
//      [65536,106496)   P per wave [64q][40k] ushort (5120 B each)
//      [106496,108544)  mL [8ks][64q] f32
//      epilogue aliases [0,69632) as mO [8ks][64c][34] f32 (two q-half passes)
#define P_OFF 65536
#define ML_OFF 106496
#define SMEM_BYTES 108544
__global__ __launch_bounds__(512, 2) void attn_kernel(const float* __restrict__ fg,
                                                      const float* __restrict__ mask,
                                                      float* __restrict__ out) {
  __shared__ __align__(16) char smem[SMEM_BYTES];
  // bijective XCD swizzle (256 % 8 == 0): 2 XCDs per batch -> 2MB working set/L2
  const int wg = blockIdx.x;
  const int wgp = (wg & 7) * 32 + (wg >> 3);
  const int b = wgp >> 6;
  const int q0 = (wgp & 63) * QB;
  const int tid = threadIdx.x;
  const int lane = tid & 63;
  const int ks = tid >> 6;    // 0..7, private K-split (512 k each)
  const int m16 = lane & 15;
  const int quad = lane >> 4;

  // fg B-fragments (64 q), loaded once from global (L2)
  bf16x8 Bf[4][2];
#pragma unroll
  for (int qf = 0; qf < 4; ++qf)
#pragma unroll
    for (int h = 0; h < 2; ++h)
      Bf[qf][h] = *(const bf16x8*)&g_fgT[b][q0 + qf * 16 + m16][h * 32 + quad * 8];

  // bgT lane-swizzled staging sources (swizzle on global side; LDS lane-ordered)
  const unsigned short* srcT[4];
#pragma unroll
  for (int t = 0; t < 4; ++t) {
    int uT = t * 64 + lane;
    int kk = uT >> 3, pos = uT & 7, j = pos ^ (kk & 7);
    srcT[t] = &g_bgT[b][ks * 512 + kk][j * 8];
  }

  // bgN per-lane base (chunk-major): chunk block ks*16, row c=m16, k-slice quad*8
  const unsigned short* pN = &g_bgN[b][ks * 16][m16][quad * 8];

  unsigned short* P = (unsigned short*)(smem + P_OFF + ks * 5120);  // [64 q][40 k]
  float* mL = (float*)(smem + ML_OFF);

  float l_run[4] = {0.f, 0.f, 0.f, 0.f};   // per-lane partial sums per q-frag
  f32x4 O[4][4];                            // [c-tile][q-frag]
#pragma unroll
  for (int t = 0; t < 4; ++t)
#pragma unroll
    for (int qf = 0; qf < 4; ++qf) O[t][qf] = (f32x4){0.f, 0.f, 0.f, 0.f};

  char* const myT = smem + ks * 8192;       // this wave's bgT staging (2 x 4KB)

  auto stageT = [&](int bufsel) {
#pragma unroll
    for (int t = 0; t < 4; ++t) {
      __builtin_amdgcn_global_load_lds(
          (const __attribute__((address_space(1))) unsigned int*)srcT[t],
          (__attribute__((address_space(3))) unsigned int*)(myT + bufsel * 4096 + t * 1024),
          16, 0, 0);
      srcT[t] += KT * CC;   // next chunk
    }
  };

  bf16x8 A0r[4], A1r[4];   // bgN register double-buffer (static-indexed)
  auto loadN = [&](bf16x8 (&A)[4], int ch) {
#pragma unroll
    for (int t = 0; t < 4; ++t)
      A[t] = *(const bf16x8*)(pN + (size_t)ch * (CC * KT) + t * 16 * KT);
  };

  // one pipeline step: compute chunk `it` from LDS buf `co` + regs Ac,
  // prefetching chunk it+1 into buf `co^1` + regs An.
  auto iter = [&](int it, int co, bf16x8 (&Ac)[4], bf16x8 (&An)[4]) {
    if (it + 1 < NITER) {
      stageT(co ^ 1);        // 4 x global_load_lds (bgT, chunk it+1)
      loadN(An, it + 1);     // 4 x global_load_dwordx4 (bgN, chunk it+1)
      // oldest-8 wait: chunk-it bgT glds AND chunk-it bgN reg loads complete
      asm volatile("s_waitcnt vmcnt(8)" ::: "memory");
    } else {
      asm volatile("s_waitcnt vmcnt(0)" ::: "memory");
    }

    const char* baseT = myT + co * 4096;

    // scores S[32k][64q] = (bg*sb)^T · (fg*sf): 4 ds_read feed 16 MFMA
    f32x4 S[4][2];
    __builtin_amdgcn_s_setprio(1);
#pragma unroll
    for (int i = 0; i < 2; ++i) {
      int kk = 16 * i + m16;
      bf16x8 T0 = *(const bf16x8*)(baseT + kk * 128 + ((quad) ^ (kk & 7)) * 16);
      bf16x8 T1 = *(const bf16x8*)(baseT + kk * 128 + ((4 + quad) ^ (kk & 7)) * 16);
#pragma unroll
      for (int qf = 0; qf < 4; ++qf) {
        f32x4 acc = {0.f, 0.f, 0.f, 0.f};
        acc = __builtin_amdgcn_mfma_f32_16x16x32_bf16(T0, Bf[qf][0], acc, 0, 0, 0);
        acc = __builtin_amdgcn_mfma_f32_16x16x32_bf16(T1, Bf[qf][1], acc, 0, 0, 0);
        S[qf][i] = acc;
      }
    }
    __builtin_amdgcn_s_setprio(0);

    // fixed-max softmax: cosines, |s| <= 1 -> p = exp(s-1); per-lane deferred sum
#pragma unroll
    for (int qf = 0; qf < 4; ++qf)
#pragma unroll
      for (int i = 0; i < 2; ++i) {
        float pe[4];
#pragma unroll
        for (int r = 0; r < 4; ++r) {
          pe[r] = __expf(S[qf][i][r] - 1.0f);
          l_run[qf] += pe[r];
        }
        // pack P -> per-wave LDS [q][k] bf16 (round-half-up via +0x8000, v_perm)
        union { float f; unsigned int u; } x0, x1, x2, x3;
        x0.f = pe[0]; x1.f = pe[1]; x2.f = pe[2]; x3.f = pe[3];
        unsigned int p01 = __builtin_amdgcn_perm(x1.u + 0x8000u, x0.u + 0x8000u, 0x07060302u);
        unsigned int p23 = __builtin_amdgcn_perm(x3.u + 0x8000u, x2.u + 0x8000u, 0x07060302u);
        *(uint2*)&P[(qf * 16 + m16) * 40 + 16 * i + quad * 4] = make_uint2(p01, p23);
      }

    // PV: O[c][q] += bg[c][k] · P[k][q]   (per-wave P + private regs: no barrier)
    bf16x8 Pf[4];
#pragma unroll
    for (int qf = 0; qf < 4; ++qf)
      Pf[qf] = *(const bf16x8*)&P[(qf * 16 + m16) * 40 + quad * 8];
    __builtin_amdgcn_s_setprio(1);
#pragma unroll
    for (int t = 0; t < 4; ++t)
#pragma unroll
      for (int qf = 0; qf < 4; ++qf)
        O[t][qf] = __builtin_amdgcn_mfma_f32_16x16x32_bf16(Ac[t], Pf[qf], O[t][qf], 0, 0, 0);
    __builtin_amdgcn_s_setprio(0);
  };

  // prologue: chunk 0 in flight (4 glds + 4 reg loads)
  stageT(0);
  loadN(A0r, 0);

  for (int it2 = 0; it2 < NITER; it2 += 2) {
    iter(it2,     0, A0r, A1r);
    iter(it2 + 1, 1, A1r, A0r);
  }

  // ---- merge 8 K-splits + epilogue (two q-half passes; mO aliases staging+P) ----
#pragma unroll
  for (int qf = 0; qf < 4; ++qf) {
    l_run[qf] += __shfl_xor(l_run[qf], 16, 64);
    l_run[qf] += __shfl_xor(l_run[qf], 32, 64);
  }
  if (quad == 0) {
#pragma unroll
    for (int qf = 0; qf < 4; ++qf) mL[ks * 64 + qf * 16 + m16] = l_run[qf];
  }
  float* mO = (float*)smem;   // [8 ks][64 c][34]
  const float* fgB = fg + (size_t)b * CC * HWN;
  const float* mk = mask + (size_t)b * HWN;
  float* outB = out + (size_t)b * CC * HWN;

#pragma unroll
  for (int half = 0; half < 2; ++half) {
    __syncthreads();   // pass 0: all waves done with staging/P reads; pass 1: reduce done
#pragma unroll
    for (int qh = 0; qh < 2; ++qh) {
      int qf = half * 2 + qh;
#pragma unroll
      for (int t = 0; t < 4; ++t)
#pragma unroll
        for (int r = 0; r < 4; ++r)
          mO[(ks * 64 + 16 * t + quad * 4 + r) * 34 + qh * 16 + m16] = O[t][qf][r];
    }
    __syncthreads();
    {
      int q = tid & 31, cb = tid >> 5;   // cb 0..15
      int qglob = q0 + half * 32 + q;
      float L = 0.f;
#pragma unroll
      for (int s = 0; s < 8; ++s) L += mL[s * 64 + half * 32 + q];
      float invL = 1.0f / L;
      float mv = mk[qglob];
#pragma unroll
      for (int e = 0; e < 4; ++e) {
        int c = cb * 4 + e;
        float acc = 0.f;
#pragma unroll
        for (int s = 0; s < 8; ++s) acc += mO[(s * 64 + c) * 34 + q];
        float att = acc * invL;
        float fgv = fgB[(size_t)c * HWN + qglob];
        outB[(size_t)c * HWN + qglob] = fgv + mv * (att - fgv);
      }
    }
  }
}

extern "C" void kernel_launch(void* const* d_in, const int* in_sizes, int n_in,
                              void* d_out, int out_size, void* d_ws, size_t ws_size,
                              hipStream_t stream) {
  const float* background = (const float*)d_in[0];
  const float* foreground = (const float*)d_in[1];
  const float* mask       = (const float*)d_in[2];
  float* out = (float*)d_out;
  prep_kernel<<<512, 256, 0, stream>>>(background, foreground);
  attn_kernel<<<dim3(HWN / QB * 4), 512, 0, stream>>>(foreground, mask, out);
}